// Round 1
// baseline (307.945 us; speedup 1.0000x reference)
//
#include <hip/hip_runtime.h>

typedef short bf16x8 __attribute__((ext_vector_type(8)));
typedef float f32x4 __attribute__((ext_vector_type(4)));

__device__ __forceinline__ unsigned short f2bf(float f) {
    union { float f; unsigned u; } a;
    a.f = f;
    unsigned u = a.u;
    u += 0x7fffu + ((u >> 16) & 1u);   // round-to-nearest-even
    return (unsigned short)(u >> 16);
}

// Convert weight w[u][n] (fp32, u-major) -> wt[n][u] (bf16, transposed), scale folded in.
__global__ void convert_w(const float* __restrict__ w, unsigned short* __restrict__ wt,
                          int mul, float scale) {
    int idx = blockIdx.x * blockDim.x + threadIdx.x;
    if (idx >= mul * mul) return;
    int n = idx / mul;   // output channel
    int k = idx % mul;   // input channel (contracted)
    wt[idx] = f2bf(w[k * mul + n] * scale);
}

// One WG (256 threads = 4 waves) handles BM=32 rows x full N=MUL outputs for one irrep block.
// GEMM rows m = z_local*D + i  (i = m-component), k = u (input mult), n = w (output mult).
template<int MUL, int D, int OFF, int GM, int GN>
__global__ __launch_bounds__(256)
void irreps_linear(const float* __restrict__ x, const unsigned short* __restrict__ wt,
                   float* __restrict__ out) {
    constexpr int BM     = 32;
    constexpr int MP     = BM * D;        // GEMM rows per WG
    constexpr int MT     = MP / 16;       // m-tiles
    constexpr int NTL    = MUL / 16;      // n-tiles
    constexpr int WM     = MT / GM;       // m-tiles per wave
    constexpr int WN     = NTL / GN;      // n-tiles per wave
    constexpr int LDA    = MUL + 8;       // A pitch (ushorts): +16B pad -> conflict-free b128 reads
    constexpr int KSTEPS = MUL / 32;
    constexpr int REG    = MUL * D;       // floats per row region
    constexpr int W4     = REG / 4;       // float4 per row region
    constexpr int LDC    = MUL + 1;
    constexpr int ABYTES = MP * LDA * 2;
    constexpr int CBYTES = (D > 1) ? MP * LDC * 4 : 0;
    constexpr int SBYTES = ABYTES > CBYTES ? ABYTES : CBYTES;

    __shared__ __align__(16) char smem[SBYTES];
    unsigned short* As = (unsigned short*)smem;

    const int  tid = threadIdx.x;
    const long z0  = (long)blockIdx.x * BM;
    const float* xr   = x   + z0 * 960 + OFF;
    float*       orow = out + z0 * 960 + OFF;

    // ---- stage A: coalesced float4 global loads -> bf16 -> de-interleaved LDS ----
    #pragma unroll
    for (int it = 0; it < (BM * W4) / 256; ++it) {
        int idx = tid + it * 256;
        int zl  = idx / W4;
        int c4  = (idx % W4) * 4;
        f32x4 v = *(const f32x4*)(xr + (long)zl * 960 + c4);
        #pragma unroll
        for (int e = 0; e < 4; ++e) {
            int c = c4 + e;                       // channel = u*D + i
            As[(zl * D + (c % D)) * LDA + (c / D)] = f2bf(v[e]);
        }
    }
    __syncthreads();

    const int lane = tid & 63;
    const int wv   = tid >> 6;
    const int wm0  = (wv / GN) * WM;
    const int wn0  = (wv % GN) * WN;
    const int lr   = lane & 15;          // row (A) / col (B,C) within 16x16 tile
    const int lk   = (lane >> 4) * 8;    // k offset within 32

    f32x4 acc[WM][WN] = {};
    #pragma unroll
    for (int ks = 0; ks < KSTEPS; ++ks) {
        const int k0 = ks * 32 + lk;
        bf16x8 bfr[WN];
        #pragma unroll
        for (int in = 0; in < WN; ++in)
            bfr[in] = *(const bf16x8*)(wt + ((wn0 + in) * 16 + lr) * MUL + k0);
        #pragma unroll
        for (int im = 0; im < WM; ++im) {
            bf16x8 afr = *(const bf16x8*)(As + ((wm0 + im) * 16 + lr) * LDA + k0);
            #pragma unroll
            for (int in = 0; in < WN; ++in)
                acc[im][in] = __builtin_amdgcn_mfma_f32_16x16x32_bf16(
                    afr, bfr[in], acc[im][in], 0, 0, 0);
        }
    }

    if constexpr (D == 1) {
        // direct stores: 16 consecutive lanes -> 16 consecutive floats (64B segments)
        #pragma unroll
        for (int im = 0; im < WM; ++im) {
            #pragma unroll
            for (int in = 0; in < WN; ++in) {
                int n  = (wn0 + in) * 16 + lr;
                int mb = (wm0 + im) * 16 + (lane >> 4) * 4;
                #pragma unroll
                for (int j = 0; j < 4; ++j)
                    orow[(long)(mb + j) * 960 + n] = acc[im][in][j];
            }
        }
    } else {
        // stage C in LDS (reuse A buffer), then fully-coalesced float4 stores
        __syncthreads();
        float* Cs = (float*)smem;
        #pragma unroll
        for (int im = 0; im < WM; ++im) {
            #pragma unroll
            for (int in = 0; in < WN; ++in) {
                int n  = (wn0 + in) * 16 + lr;
                int mb = (wm0 + im) * 16 + (lane >> 4) * 4;
                #pragma unroll
                for (int j = 0; j < 4; ++j)
                    Cs[(mb + j) * LDC + n] = acc[im][in][j];
            }
        }
        __syncthreads();
        #pragma unroll
        for (int it = 0; it < (BM * W4) / 256; ++it) {
            int idx = tid + it * 256;
            int zl  = idx / W4;
            int c4  = (idx % W4) * 4;
            f32x4 v;
            #pragma unroll
            for (int e = 0; e < 4; ++e) {
                int c = c4 + e;                   // out channel = n*D + i
                v[e] = Cs[(zl * D + (c % D)) * LDC + (c / D)];
            }
            *(f32x4*)(orow + (long)zl * 960 + c4) = v;
        }
    }
}

extern "C" void kernel_launch(void* const* d_in, const int* in_sizes, int n_in,
                              void* d_out, int out_size, void* d_ws, size_t ws_size,
                              hipStream_t stream) {
    const float* x  = (const float*)d_in[0];
    const float* w0 = (const float*)d_in[1];
    const float* w1 = (const float*)d_in[2];
    const float* w2 = (const float*)d_in[3];
    float* out = (float*)d_out;
    unsigned short* wt = (unsigned short*)d_ws;   // needs 86016*2 = 168 KB scratch

    const int N  = in_sizes[0] / 960;
    const int nb = N / 32;

    convert_w<<<(256 * 256) / 256, 256, 0, stream>>>(w0, wt,         256, 0.0625f);
    convert_w<<<(128 * 128) / 256, 256, 0, stream>>>(w1, wt + 65536, 128, 0.08838834764831845f);
    convert_w<<<( 64 *  64) / 256, 256, 0, stream>>>(w2, wt + 81920,  64, 0.125f);

    irreps_linear<256, 1,   0, 1, 4><<<nb, 256, 0, stream>>>(x, wt,         out);
    irreps_linear<128, 3, 256, 2, 2><<<nb, 256, 0, stream>>>(x, wt + 65536, out);
    irreps_linear< 64, 5, 640, 2, 2><<<nb, 256, 0, stream>>>(x, wt + 81920, out);
}

// Round 2
// 296.667 us; speedup vs baseline: 1.0380x; 1.0380x over previous
//
#include <hip/hip_runtime.h>

typedef short bf16x8 __attribute__((ext_vector_type(8)));
typedef float f32x4 __attribute__((ext_vector_type(4)));

__device__ __forceinline__ unsigned short f2bf(float f) {
    union { float f; unsigned u; } a;
    a.f = f;
    unsigned u = a.u;
    u += 0x7fffu + ((u >> 16) & 1u);   // round-to-nearest-even
    return (unsigned short)(u >> 16);
}

__device__ __forceinline__ f32x4 mfma16(bf16x8 a, bf16x8 b, f32x4 c) {
    return __builtin_amdgcn_mfma_f32_16x16x32_bf16(a, b, c, 0, 0, 0);
}

// w[u][n] fp32 -> wt[n][u] bf16 transposed, scale folded.
__global__ void convert_w(const float* __restrict__ w, unsigned short* __restrict__ wt,
                          int mul, float scale) {
    int idx = blockIdx.x * blockDim.x + threadIdx.x;
    if (idx >= mul * mul) return;
    int n = idx / mul;
    int k = idx % mul;
    wt[idx] = f2bf(w[k * mul + n] * scale);
}

// Fused: one WG (512 thr = 8 waves) does BM=32 full rows: all three irrep blocks.
// LDS A tiles (bf16, padded):  A0 [32][264]  A1 [96][136]  A2 [160][72]  = 66048 B
// Epilogue reuses the same LDS for C staging (C0 32x257, C1 96x129, C2 160x65 f32).
__global__ __launch_bounds__(512, 4)
void fused_linear(const float* __restrict__ x, const unsigned short* __restrict__ wt,
                  float* __restrict__ out) {
    __shared__ __align__(16) char smem[66048];
    unsigned short* As0 = (unsigned short*)smem;     // [32][264]
    unsigned short* As1 = As0 + 32 * 264;            // [96][136]
    unsigned short* As2 = As1 + 96 * 136;            // [160][72]
    float* Cs = (float*)smem;

    const int  tid = threadIdx.x;
    const long z0  = (long)blockIdx.x * 32;
    const float* xr   = x   + z0 * 960;
    float*       orow = out + z0 * 960;

    // ---- stage A: fully-contiguous float4 stream -> bf16 -> de-interleaved LDS ----
    #pragma unroll
    for (int it = 0; it < 15; ++it) {
        int idx = tid + it * 512;                    // 0..7679
        f32x4 v = *(const f32x4*)(xr + (long)idx * 4);
        int zl = idx / 240;
        int c4 = (idx % 240) * 4;
        #pragma unroll
        for (int e = 0; e < 4; ++e) {
            int c = c4 + e;
            unsigned short b = f2bf(v[e]);
            if (c < 256) {
                As0[zl * 264 + c] = b;
            } else if (c < 640) {
                int cc = c - 256;
                As1[(zl * 3 + cc % 3) * 136 + cc / 3] = b;
            } else {
                int cc = c - 640;
                As2[(zl * 5 + cc % 5) * 72 + cc / 5] = b;
            }
        }
    }
    __syncthreads();

    const int lane = tid & 63;
    const int wv   = tid >> 6;      // 0..7
    const int lr   = lane & 15;
    const int q    = lane >> 4;     // 0..3
    const int lk   = q * 8;

    // ---- block 0: M=32(2 mt) x N=256(16 nt), K=256.  GN=8: wave -> nt [2wv,2wv+2) ----
    f32x4 acc0[2][2] = {};
    {
        const unsigned short* w0 = wt;
        #pragma unroll
        for (int ks = 0; ks < 8; ++ks) {
            int k0 = ks * 32 + lk;
            bf16x8 b0 = *(const bf16x8*)(w0 + ((wv * 2 + 0) * 16 + lr) * 256 + k0);
            bf16x8 b1 = *(const bf16x8*)(w0 + ((wv * 2 + 1) * 16 + lr) * 256 + k0);
            #pragma unroll
            for (int im = 0; im < 2; ++im) {
                bf16x8 a = *(const bf16x8*)(As0 + (im * 16 + lr) * 264 + k0);
                acc0[im][0] = mfma16(a, b0, acc0[im][0]);
                acc0[im][1] = mfma16(a, b1, acc0[im][1]);
            }
        }
    }

    // ---- block 1: M=96(6 mt) x N=128(8 nt), K=128.  GM=2,GN=4 ----
    const int r1 = wv >> 2, c1 = wv & 3;
    f32x4 acc1[3][2] = {};
    {
        const unsigned short* w1 = wt + 65536;
        #pragma unroll
        for (int ks = 0; ks < 4; ++ks) {
            int k0 = ks * 32 + lk;
            bf16x8 b0 = *(const bf16x8*)(w1 + ((c1 * 2 + 0) * 16 + lr) * 128 + k0);
            bf16x8 b1 = *(const bf16x8*)(w1 + ((c1 * 2 + 1) * 16 + lr) * 128 + k0);
            #pragma unroll
            for (int im = 0; im < 3; ++im) {
                bf16x8 a = *(const bf16x8*)(As1 + ((r1 * 3 + im) * 16 + lr) * 136 + k0);
                acc1[im][0] = mfma16(a, b0, acc1[im][0]);
                acc1[im][1] = mfma16(a, b1, acc1[im][1]);
            }
        }
    }

    // ---- block 2: M=160(10 mt) x N=64(4 nt), K=64.  GM=2,GN=4 (WN=1) ----
    f32x4 acc2[5] = {};
    {
        const unsigned short* w2 = wt + 81920;
        #pragma unroll
        for (int ks = 0; ks < 2; ++ks) {
            int k0 = ks * 32 + lk;
            bf16x8 b0 = *(const bf16x8*)(w2 + (c1 * 16 + lr) * 64 + k0);
            #pragma unroll
            for (int im = 0; im < 5; ++im) {
                bf16x8 a = *(const bf16x8*)(As2 + ((r1 * 5 + im) * 16 + lr) * 72 + k0);
                acc2[im] = mfma16(a, b0, acc2[im]);
            }
        }
    }
    __syncthreads();   // all A reads done; LDS now reusable for C

    // ---- epilogue block 0: C -> LDS -> contiguous float4 stores ----
    #pragma unroll
    for (int im = 0; im < 2; ++im)
        #pragma unroll
        for (int in = 0; in < 2; ++in) {
            int col = (wv * 2 + in) * 16 + lr;
            int row = im * 16 + q * 4;
            #pragma unroll
            for (int j = 0; j < 4; ++j)
                Cs[(row + j) * 257 + col] = acc0[im][in][j];
        }
    __syncthreads();
    #pragma unroll
    for (int it = 0; it < 4; ++it) {
        int idx = tid + it * 512;                    // 0..2047
        int zl = idx / 64, c4 = (idx % 64) * 4;
        f32x4 v;
        #pragma unroll
        for (int e = 0; e < 4; ++e) v[e] = Cs[zl * 257 + c4 + e];
        *(f32x4*)(orow + (long)zl * 960 + c4) = v;
    }
    __syncthreads();

    // ---- epilogue block 1 ----
    #pragma unroll
    for (int im = 0; im < 3; ++im)
        #pragma unroll
        for (int in = 0; in < 2; ++in) {
            int col = (c1 * 2 + in) * 16 + lr;
            int row = (r1 * 3 + im) * 16 + q * 4;
            #pragma unroll
            for (int j = 0; j < 4; ++j)
                Cs[(row + j) * 129 + col] = acc1[im][in][j];
        }
    __syncthreads();
    #pragma unroll
    for (int it = 0; it < 6; ++it) {
        int idx = tid + it * 512;                    // 0..3071
        int zl = idx / 96, c4 = (idx % 96) * 4;
        f32x4 v;
        #pragma unroll
        for (int e = 0; e < 4; ++e) {
            int c = c4 + e;
            v[e] = Cs[(zl * 3 + c % 3) * 129 + c / 3];
        }
        *(f32x4*)(orow + (long)zl * 960 + 256 + c4) = v;
    }
    __syncthreads();

    // ---- epilogue block 2 ----
    #pragma unroll
    for (int im = 0; im < 5; ++im) {
        int col = c1 * 16 + lr;
        int row = (r1 * 5 + im) * 16 + q * 4;
        #pragma unroll
        for (int j = 0; j < 4; ++j)
            Cs[(row + j) * 65 + col] = acc2[im][j];
    }
    __syncthreads();
    #pragma unroll
    for (int it = 0; it < 5; ++it) {
        int idx = tid + it * 512;                    // 0..2559
        int zl = idx / 80, c4 = (idx % 80) * 4;
        f32x4 v;
        #pragma unroll
        for (int e = 0; e < 4; ++e) {
            int c = c4 + e;
            v[e] = Cs[(zl * 5 + c % 5) * 65 + c / 5];
        }
        *(f32x4*)(orow + (long)zl * 960 + 640 + c4) = v;
    }
}

extern "C" void kernel_launch(void* const* d_in, const int* in_sizes, int n_in,
                              void* d_out, int out_size, void* d_ws, size_t ws_size,
                              hipStream_t stream) {
    const float* x  = (const float*)d_in[0];
    const float* w0 = (const float*)d_in[1];
    const float* w1 = (const float*)d_in[2];
    const float* w2 = (const float*)d_in[3];
    float* out = (float*)d_out;
    unsigned short* wt = (unsigned short*)d_ws;   // 86016 * 2 B = 168 KB

    const int N  = in_sizes[0] / 960;
    const int nb = N / 32;

    convert_w<<<(256 * 256) / 256, 256, 0, stream>>>(w0, wt,         256, 0.0625f);
    convert_w<<<(128 * 128) / 256, 256, 0, stream>>>(w1, wt + 65536, 128, 0.08838834764831845f);
    convert_w<<<( 64 *  64) / 256, 256, 0, stream>>>(w2, wt + 81920,  64, 0.125f);

    fused_linear<<<nb, 512, 0, stream>>>(x, wt, out);
}